// Round 3
// baseline (368.615 us; speedup 1.0000x reference)
//
#include <hip/hip_runtime.h>

// HarmonicFullyConnectedTensorProduct, lmax=2, MUL=64, B=1024, 11 paths.
// out[z,w,k] += sum_{u,v,m,n} x1[z,u,m] x2[z,v,n] W[p,w,u,v] C_p[m,n,k]
//
// Round 3: prep kernels hoist all conversion work out of the hot loop.
//   prep_w : W fp32 [p][w][u][v] -> bf16 Wb [p][u][w][v]
//   prep_c1: c1[p][z*64+u][k*N1+n] = sum_m x1[z,u,m] C[m,n,k]   (fp32, ws)
//   tp_main: per (path, z-tile): K-loop over u:
//       T-form: sT[(z*K1+k)][v] = bf16(sum_n x2[z,v,n] * c1[z,u,k,n])
//               (x2 hoisted in regs for the whole block; c1 via s_load)
//       MFMA  : D[w, z*K1+k] += Wb[u] @ sT   (mfma_f32_16x16x32_bf16)
// Wave = one 16-row w-tile, all col-tiles. 2 barriers/u. ~3 blocks/CU.

#define NTHREADS 256

typedef __attribute__((ext_vector_type(4))) float f32x4;
typedef __attribute__((ext_vector_type(8))) short s16x8;

__device__ __forceinline__ unsigned short f2bf(float x) {
    union { float f; unsigned u; } v; v.f = x;
    unsigned r = v.u + 0x7fffu + ((v.u >> 16) & 1u);   // RNE
    return (unsigned short)(r >> 16);
}

// ---------------- prep kernels ----------------

__global__ __launch_bounds__(NTHREADS) void prep_w(const float* __restrict__ W,
                                                   unsigned short* __restrict__ Wb)
{
    int id = blockIdx.x * NTHREADS + threadIdx.x;   // (p,u,w,v4): 11*64*64*16
    int v4 = (id & 15) << 2;
    int w  = (id >> 4) & 63;
    int u  = (id >> 10) & 63;
    int p  = id >> 16;
    float4 f = *(const float4*)(W + (((size_t)p * 64 + w) * 64 + u) * 64 + v4);
    ushort4 h;
    h.x = f2bf(f.x); h.y = f2bf(f.y); h.z = f2bf(f.z); h.w = f2bf(f.w);
    *(ushort4*)(Wb + (((size_t)p * 64 + u) * 64 + w) * 64 + v4) = h;
}

struct PrepArgs {
    const float* x1[3];
    const float* C[11];
    float*       c1[11];
    int M1[11], N1[11], K1[11], S1[11], l1[11];
};

__global__ __launch_bounds__(NTHREADS) void prep_c1(PrepArgs a)
{
    const int p  = blockIdx.y;
    const int id = blockIdx.x * NTHREADS + threadIdx.x;
    const int j  = id & 31;
    const int row = id >> 5;                 // z*64+u, < 65536
    const int N1 = a.N1[p], K1 = a.K1[p], M1 = a.M1[p], S1 = a.S1[p];
    if (j >= K1 * N1) return;
    const int k = j / N1, n = j - k * N1;
    const float* x1 = a.x1[a.l1[p]] + (size_t)row * M1;
    const float* C  = a.C[p];
    float s = 0.f;
    for (int m = 0; m < M1; ++m) s += x1[m] * C[(m * N1 + n) * K1 + k];
    a.c1[p][(size_t)row * S1 + j] = s;
}

// ---------------- main kernel ----------------

struct KArgs {
    const float*          x2[3];
    const unsigned short* Wb;
    const float*          c1[11];
    float*                out;
};

template <int N1, int K1, int KOFF, int ZT, int S1>
__device__ __forceinline__ void run_path(const float* __restrict__ x2g,
                                         const unsigned short* __restrict__ Wbp,
                                         const float* __restrict__ c1p,
                                         float* __restrict__ outg, int local,
                                         unsigned short* __restrict__ sW,   // [64][72]
                                         unsigned short* __restrict__ sT)   // [ZT*K1][72]
{
    constexpr int NC = ZT * K1 / 16;   // col-tiles
    constexpr int NI = ZT / 4;         // T-form iters/thread
    const int t = threadIdx.x, lane = t & 63, wave = t >> 6;
    const int ln = lane & 15, q = lane >> 4;
    const int z0 = local * ZT;

    // hoist x2 for this block's z-range into registers (reused for all 64 u)
    float xr[NI][N1];
#pragma unroll
    for (int i = 0; i < NI; ++i) {
        const int z = z0 + i * 4 + wave;
        const float* xp = x2g + ((size_t)z * 64 + lane) * N1;
#pragma unroll
        for (int n = 0; n < N1; ++n) xr[i][n] = xp[n];
    }

    f32x4 acc[NC];
#pragma unroll
    for (int c = 0; c < NC; ++c) acc[c] = (f32x4){0.f, 0.f, 0.f, 0.f};

    for (int u = 0; u < 64; ++u) {
        // W stage: issue global loads early, store to LDS after T-form
        const unsigned short* wsrc = Wbp + (size_t)u * 4096;
        s16x8 wreg0 = *(const s16x8*)(wsrc + t * 8);
        s16x8 wreg1 = *(const s16x8*)(wsrc + 2048 + t * 8);

        // T-form: thread = (z = i*4+wave, v = lane)
#pragma unroll
        for (int i = 0; i < NI; ++i) {
            const int z = i * 4 + wave;
            int off = ((z0 + z) * 64 + u) * S1;
            off = __builtin_amdgcn_readfirstlane(off);   // force scalar loads
            const float* cp = c1p + off;
            float c1v[S1];
#pragma unroll
            for (int jj = 0; jj < S1 / 4; ++jj) {
                float4 f = *(const float4*)(cp + jj * 4);
                c1v[jj * 4 + 0] = f.x; c1v[jj * 4 + 1] = f.y;
                c1v[jj * 4 + 2] = f.z; c1v[jj * 4 + 3] = f.w;
            }
#pragma unroll
            for (int k = 0; k < K1; ++k) {
                float s = 0.f;
#pragma unroll
                for (int n = 0; n < N1; ++n) s += xr[i][n] * c1v[k * N1 + n];
                sT[(z * K1 + k) * 72 + lane] = f2bf(s);
            }
        }
        // store W regs to LDS (stride-72 rows: 2-way bank aliasing = free)
        {
            int i0 = t * 8;
            sW[0] = sW[0];  // no-op to keep layout clear
            *(s16x8*)&sW[(i0 >> 6) * 72 + (i0 & 63)] = wreg0;
            int i1 = 2048 + t * 8;
            *(s16x8*)&sW[(i1 >> 6) * 72 + (i1 & 63)] = wreg1;
        }
        __syncthreads();

        // MFMA: wave owns w-tile = wave, all NC col-tiles; K=64 per u
#pragma unroll
        for (int s = 0; s < 2; ++s) {
            s16x8 af = *(const s16x8*)&sW[(wave * 16 + ln) * 72 + s * 32 + q * 8];
#pragma unroll
            for (int c = 0; c < NC; ++c) {
                s16x8 bf = *(const s16x8*)&sT[(c * 16 + ln) * 72 + s * 32 + q * 8];
                acc[c] = __builtin_amdgcn_mfma_f32_16x16x32_bf16(af, bf, acc[c], 0, 0, 0);
            }
        }
        __syncthreads();
    }

    // epilogue: D row = wave*16+q*4+r (=w), col = c*16+ln (= z*K1+k)
#pragma unroll
    for (int c = 0; c < NC; ++c) {
        const int col = c * 16 + ln;
        const int z = col / K1, k = col - z * K1;
        float* op = outg + (size_t)(z0 + z) * 576 + (wave * 16 + q * 4) * 9 + KOFF + k;
#pragma unroll
        for (int r = 0; r < 4; ++r) atomicAdd(op + r * 9, acc[c][r]);
    }
}

__global__ __launch_bounds__(NTHREADS, 3) void tp_main(KArgs a)
{
    __shared__ __align__(16) unsigned short sW[64 * 72];    //  9216 B
    __shared__ __align__(16) unsigned short sT[192 * 72];   // 27648 B

    const int bid = blockIdx.x;
    const int starts[12] = {0, 16, 48, 112, 128, 160, 192, 224, 256, 288, 320, 384};
    int p = 0;
#pragma unroll
    for (int i = 1; i < 12; ++i) p += (bid >= starts[i]) ? 1 : 0;
    const int local = bid - starts[p];
    const unsigned short* Wbp = a.Wb + (size_t)p * 262144;

    switch (p) {                       //        N1 K1 KOFF ZT S1
        case 0:  run_path<1,1,0,64, 4>(a.x2[0], Wbp, a.c1[0],  a.out, local, sW, sT); break;
        case 1:  run_path<3,3,1,32,12>(a.x2[1], Wbp, a.c1[1],  a.out, local, sW, sT); break;
        case 2:  run_path<5,5,4,16,28>(a.x2[2], Wbp, a.c1[2],  a.out, local, sW, sT); break;
        case 3:  run_path<1,3,1,64, 4>(a.x2[0], Wbp, a.c1[3],  a.out, local, sW, sT); break;
        case 4:  run_path<3,1,0,32, 4>(a.x2[1], Wbp, a.c1[4],  a.out, local, sW, sT); break;
        case 5:  run_path<3,5,4,32,16>(a.x2[1], Wbp, a.c1[5],  a.out, local, sW, sT); break;
        case 6:  run_path<5,3,1,32,16>(a.x2[2], Wbp, a.c1[6],  a.out, local, sW, sT); break;
        case 7:  run_path<1,5,4,32, 8>(a.x2[0], Wbp, a.c1[7],  a.out, local, sW, sT); break;
        case 8:  run_path<3,3,1,32,12>(a.x2[1], Wbp, a.c1[8],  a.out, local, sW, sT); break;
        case 9:  run_path<5,1,0,32, 8>(a.x2[2], Wbp, a.c1[9],  a.out, local, sW, sT); break;
        case 10: run_path<5,5,4,16,28>(a.x2[2], Wbp, a.c1[10], a.out, local, sW, sT); break;
        default: break;
    }
}

// ---------------- launch ----------------

extern "C" void kernel_launch(void* const* d_in, const int* in_sizes, int n_in,
                              void* d_out, int out_size, void* d_ws, size_t ws_size,
                              hipStream_t stream)
{
    static const int M1t[11] = {1,1,1,3,3,3,3,5,5,5,5};
    static const int N1t[11] = {1,3,5,1,3,3,5,1,3,5,5};
    static const int K1t[11] = {1,3,5,3,1,5,3,5,3,1,5};
    static const int S1t[11] = {4,12,28,4,4,16,16,8,12,8,28};
    static const int l1t[11] = {0,0,0,1,1,1,1,2,2,2,2};
    static const int cum[11] = {0,4,16,44,48,52,68,84,92,104,112};  // prefix of S1

    unsigned short* Wb = (unsigned short*)d_ws;                  // 5.77 MB
    float* c1base = (float*)((char*)d_ws + (6u << 20));          // 36.7 MB

    PrepArgs pa;
    pa.x1[0] = (const float*)d_in[0];
    pa.x1[1] = (const float*)d_in[2];
    pa.x1[2] = (const float*)d_in[4];
    for (int p = 0; p < 11; ++p) {
        pa.C[p]  = (const float*)d_in[7 + p];
        pa.c1[p] = c1base + (size_t)65536 * cum[p];
        pa.M1[p] = M1t[p]; pa.N1[p] = N1t[p]; pa.K1[p] = K1t[p];
        pa.S1[p] = S1t[p]; pa.l1[p] = l1t[p];
    }

    KArgs a;
    a.x2[0] = (const float*)d_in[1];
    a.x2[1] = (const float*)d_in[3];
    a.x2[2] = (const float*)d_in[5];
    a.Wb = Wb;
    for (int p = 0; p < 11; ++p) a.c1[p] = pa.c1[p];
    a.out = (float*)d_out;

    prep_w<<<dim3(720896 / NTHREADS), NTHREADS, 0, stream>>>((const float*)d_in[6], Wb);
    prep_c1<<<dim3(8192, 11), NTHREADS, 0, stream>>>(pa);
    hipMemsetAsync(d_out, 0, (size_t)out_size * sizeof(float), stream);
    tp_main<<<dim3(384), NTHREADS, 0, stream>>>(a);
}

// Round 4
// 297.977 us; speedup vs baseline: 1.2371x; 1.2371x over previous
//
#include <hip/hip_runtime.h>

// HarmonicFullyConnectedTensorProduct, lmax=2, MUL=64, B=1024, 11 paths.
// out[z,w,k] += sum_{u,v,m,n} x1[z,u,m] x2[z,v,n] W[p,w,u,v] C_p[m,n,k]
//
// Round 4: single main kernel; c1 built in LDS per block (no HBM round-trip),
// u-split 4 -> 2048 blocks (~3 resident/CU for phase overlap).
//   prep_w : W fp32 [p][w][u][v] -> bf16 Wb [p][u][w][v]  (ws)
//   tp_main: block = (path, z-tile, u-chunk of 16):
//     once: sc1[(z*16+uu)*S1 + k*N1+n] = sum_m x1[z,u0+uu,m] C[m,n,k]
//     per u: T-form sT[(z*K1+k)][v] = bf16(sum_n x2[z,v,n]*sc1[...])
//            MFMA   D[w, z*K1+k]   += Wb[u] @ sT    (16x16x32 bf16)
//     epilogue: fp32 atomicAdd into out[z][w][KOFF+k]

#define NTHREADS 256
#define UC 16            // u-chunk per block
#define USPLIT 4

typedef __attribute__((ext_vector_type(4))) float f32x4;
typedef __attribute__((ext_vector_type(8))) short s16x8;

__device__ __forceinline__ unsigned short f2bf(float x) {
    union { float f; unsigned u; } v; v.f = x;
    unsigned r = v.u + 0x7fffu + ((v.u >> 16) & 1u);   // RNE
    return (unsigned short)(r >> 16);
}

// ---------------- prep: W -> bf16, [p][u][w][v] ----------------

__global__ __launch_bounds__(NTHREADS) void prep_w(const float* __restrict__ W,
                                                   unsigned short* __restrict__ Wb)
{
    int id = blockIdx.x * NTHREADS + threadIdx.x;   // (p,u,w,v4): 11*64*64*16
    int v4 = (id & 15) << 2;
    int w  = (id >> 4) & 63;
    int u  = (id >> 10) & 63;
    int p  = id >> 16;
    float4 f = *(const float4*)(W + (((size_t)p * 64 + w) * 64 + u) * 64 + v4);
    ushort4 h;
    h.x = f2bf(f.x); h.y = f2bf(f.y); h.z = f2bf(f.z); h.w = f2bf(f.w);
    *(ushort4*)(Wb + (((size_t)p * 64 + u) * 64 + w) * 64 + v4) = h;
}

// ---------------- main ----------------

struct KArgs {
    const float*          x1[3];
    const float*          x2[3];
    const unsigned short* Wb;
    const float*          C[11];
    float*                out;
};

#define SMEM_BYTES 49920

template <int M1, int N1, int K1, int KOFF, int ZT, int S1>
__device__ __forceinline__ void run_path(const float* __restrict__ x1g,
                                         const float* __restrict__ x2g,
                                         const unsigned short* __restrict__ Wbp,
                                         const float* __restrict__ Cg,
                                         float* __restrict__ outg, int local,
                                         char* __restrict__ smem)
{
    constexpr int KN = K1 * N1;
    constexpr int NC = ZT * K1 / 16;   // MFMA col-tiles
    constexpr int NI = ZT / 4;         // T-form z-iters per thread

    unsigned short* sW  = (unsigned short*)smem;                    // [64][72]
    unsigned short* sT  = sW + 64 * 72;                             // [ZT*K1][72]
    float*          sc1 = (float*)(smem + 9216 + ZT * K1 * 144);    // [ZT*UC][S1]
    float*          sC  = sc1 + ZT * UC * S1;                       // [M1*N1*K1]

    const int t = threadIdx.x, lane = t & 63, wave = t >> 6;
    const int ln = lane & 15, q = lane >> 4;
    const int ztile = local >> 2;
    const int usub  = local & 3;
    const int z0 = ztile * ZT;
    const int u0 = usub * UC;

    for (int i = t; i < M1 * N1 * K1; i += NTHREADS) sC[i] = Cg[i];
    __syncthreads();

    // ---- build c1 slab once: sc1[(z*UC+uu)*S1 + (k*N1+n)]
    for (int i = t; i < ZT * UC * KN; i += NTHREADS) {
        int z  = i / (UC * KN);
        int r  = i - z * (UC * KN);
        int uu = r / KN;
        int j  = r - uu * KN;
        int k  = j / N1, n = j - k * N1;
        const float* x1r = x1g + ((size_t)(z0 + z) * 64 + u0 + uu) * M1;
        float s = 0.f;
#pragma unroll
        for (int m = 0; m < M1; ++m) s += x1r[m] * sC[(m * N1 + n) * K1 + k];
        sc1[(z * UC + uu) * S1 + j] = s;
    }

    // ---- hoist x2 for this block's z-range (reused across all u)
    float xr[NI][N1];
#pragma unroll
    for (int i = 0; i < NI; ++i) {
        const int z = z0 + i * 4 + wave;
        const float* xp = x2g + ((size_t)z * 64 + lane) * N1;
#pragma unroll
        for (int n = 0; n < N1; ++n) xr[i][n] = xp[n];
    }

    f32x4 acc[NC];
#pragma unroll
    for (int c = 0; c < NC; ++c) acc[c] = (f32x4){0.f, 0.f, 0.f, 0.f};

    __syncthreads();

    for (int uu = 0; uu < UC; ++uu) {
        // W stage: issue global loads early, store to LDS after T-form
        const unsigned short* wsrc = Wbp + (size_t)(u0 + uu) * 4096;
        s16x8 wreg0 = *(const s16x8*)(wsrc + t * 8);
        s16x8 wreg1 = *(const s16x8*)(wsrc + 2048 + t * 8);

        // T-form: thread = (z = i*4+wave, v = lane)
#pragma unroll
        for (int i = 0; i < NI; ++i) {
            const int z = i * 4 + wave;
            const float4* cp = (const float4*)&sc1[(z * UC + uu) * S1];
            float c1v[S1];
#pragma unroll
            for (int jj = 0; jj < S1 / 4; ++jj) {
                float4 f = cp[jj];
                c1v[jj * 4 + 0] = f.x; c1v[jj * 4 + 1] = f.y;
                c1v[jj * 4 + 2] = f.z; c1v[jj * 4 + 3] = f.w;
            }
#pragma unroll
            for (int k = 0; k < K1; ++k) {
                float s = 0.f;
#pragma unroll
                for (int n = 0; n < N1; ++n) s += xr[i][n] * c1v[k * N1 + n];
                sT[(z * K1 + k) * 72 + lane] = f2bf(s);
            }
        }
        // store W regs (stride-72 rows; 2-way bank aliasing = free)
        {
            int i0 = t * 8;
            *(s16x8*)&sW[(i0 >> 6) * 72 + (i0 & 63)] = wreg0;
            int i1 = 2048 + t * 8;
            *(s16x8*)&sW[(i1 >> 6) * 72 + (i1 & 63)] = wreg1;
        }
        __syncthreads();

        // MFMA: wave = w-tile, all NC col-tiles; K=64 (v) per u
#pragma unroll
        for (int s = 0; s < 2; ++s) {
            s16x8 af = *(const s16x8*)&sW[(wave * 16 + ln) * 72 + s * 32 + q * 8];
#pragma unroll
            for (int c = 0; c < NC; ++c) {
                s16x8 bf = *(const s16x8*)&sT[(c * 16 + ln) * 72 + s * 32 + q * 8];
                acc[c] = __builtin_amdgcn_mfma_f32_16x16x32_bf16(af, bf, acc[c], 0, 0, 0);
            }
        }
        __syncthreads();
    }

    // epilogue: D row = wave*16+q*4+r (=w), col = c*16+ln (= z*K1+k)
#pragma unroll
    for (int c = 0; c < NC; ++c) {
        const int col = c * 16 + ln;
        const int z = col / K1, k = col - z * K1;
        float* op = outg + (size_t)(z0 + z) * 576 + (wave * 16 + q * 4) * 9 + KOFF + k;
#pragma unroll
        for (int r = 0; r < 4; ++r) atomicAdd(op + r * 9, acc[c][r]);
    }
}

__global__ __launch_bounds__(NTHREADS, 3) void tp_main(KArgs a)
{
    __shared__ __align__(16) char smem[SMEM_BYTES];

    const int bid = blockIdx.x;
    // blocks/path: ZT=32 -> 128, ZT=16 -> 256
    const int starts[12] = {0, 128, 256, 512, 640, 768, 1024, 1280, 1536, 1664, 1792, 2048};
    int p = 0;
#pragma unroll
    for (int i = 1; i < 12; ++i) p += (bid >= starts[i]) ? 1 : 0;
    const int local = bid - starts[p];
    const unsigned short* Wbp = a.Wb + (size_t)p * 262144;

    switch (p) {                 //  M1 N1 K1 KOFF ZT S1
        case 0:  run_path<1,1,1,0,32, 4>(a.x1[0], a.x2[0], Wbp, a.C[0],  a.out, local, smem); break;
        case 1:  run_path<1,3,3,1,32,12>(a.x1[0], a.x2[1], Wbp, a.C[1],  a.out, local, smem); break;
        case 2:  run_path<1,5,5,4,16,28>(a.x1[0], a.x2[2], Wbp, a.C[2],  a.out, local, smem); break;
        case 3:  run_path<3,1,3,1,32, 4>(a.x1[1], a.x2[0], Wbp, a.C[3],  a.out, local, smem); break;
        case 4:  run_path<3,3,1,0,32, 4>(a.x1[1], a.x2[1], Wbp, a.C[4],  a.out, local, smem); break;
        case 5:  run_path<3,3,5,4,16,16>(a.x1[1], a.x2[1], Wbp, a.C[5],  a.out, local, smem); break;
        case 6:  run_path<3,5,3,1,16,16>(a.x1[1], a.x2[2], Wbp, a.C[6],  a.out, local, smem); break;
        case 7:  run_path<5,1,5,4,16, 8>(a.x1[2], a.x2[0], Wbp, a.C[7],  a.out, local, smem); break;
        case 8:  run_path<5,3,3,1,32,12>(a.x1[2], a.x2[1], Wbp, a.C[8],  a.out, local, smem); break;
        case 9:  run_path<5,5,1,0,32, 8>(a.x1[2], a.x2[2], Wbp, a.C[9],  a.out, local, smem); break;
        case 10: run_path<5,5,5,4,16,28>(a.x1[2], a.x2[2], Wbp, a.C[10], a.out, local, smem); break;
        default: break;
    }
}

// ---------------- launch ----------------

extern "C" void kernel_launch(void* const* d_in, const int* in_sizes, int n_in,
                              void* d_out, int out_size, void* d_ws, size_t ws_size,
                              hipStream_t stream)
{
    unsigned short* Wb = (unsigned short*)d_ws;   // 5.77 MB

    KArgs a;
    // dict order: x1_l0, x2_l0, x1_l1, x2_l1, x1_l2, x2_l2, W, C_0..C_10
    a.x1[0] = (const float*)d_in[0];
    a.x2[0] = (const float*)d_in[1];
    a.x1[1] = (const float*)d_in[2];
    a.x2[1] = (const float*)d_in[3];
    a.x1[2] = (const float*)d_in[4];
    a.x2[2] = (const float*)d_in[5];
    a.Wb = Wb;
    for (int p = 0; p < 11; ++p) a.C[p] = (const float*)d_in[7 + p];
    a.out = (float*)d_out;

    prep_w<<<dim3(720896 / NTHREADS), NTHREADS, 0, stream>>>((const float*)d_in[6], Wb);
    hipMemsetAsync(d_out, 0, (size_t)out_size * sizeof(float), stream);
    tp_main<<<dim3(2048), NTHREADS, 0, stream>>>(a);
}